// Round 8
// baseline (891.422 us; speedup 1.0000x reference)
//
#include <hip/hip_runtime.h>
#include <hip/hip_fp16.h>
#include <math.h>

#define NH 5
#define NC 64
#define ED 16
#define HC 320   // NH*NC
#define CH 32    // CSR slots per wave window in gat_fused

typedef _Float16 h2  __attribute__((ext_vector_type(2)));
typedef _Float16 v4h __attribute__((ext_vector_type(4)));
typedef _Float16 v8h __attribute__((ext_vector_type(8)));
typedef float    v4f __attribute__((ext_vector_type(4)));

// ---------------- wave64 sum via single-instruction DPP adds ----------------
// 10-chain interleave proven across 4 passing runs; do NOT widen (R5: 20 chains
// exposed the DPP read-after-VALU-write hazard the compiler can't see in asm).
__device__ __forceinline__ float wave_sum_all(float x) {
    asm("v_add_f32_dpp %0, %1, %0 quad_perm:[1,0,3,2] row_mask:0xf bank_mask:0xf"
        : "+v"(x) : "v"(x));
    asm("v_add_f32_dpp %0, %1, %0 quad_perm:[2,3,0,1] row_mask:0xf bank_mask:0xf"
        : "+v"(x) : "v"(x));
    asm("v_add_f32_dpp %0, %1, %0 row_half_mirror row_mask:0xf bank_mask:0xf"
        : "+v"(x) : "v"(x));
    asm("v_add_f32_dpp %0, %1, %0 row_mirror row_mask:0xf bank_mask:0xf"
        : "+v"(x) : "v"(x));
    asm("v_add_f32_dpp %0, %1, %0 row_bcast:15 row_mask:0xa bank_mask:0xf"
        : "+v"(x) : "v"(x));
    asm("v_add_f32_dpp %0, %1, %0 row_bcast:31 row_mask:0xc bank_mask:0xf"
        : "+v"(x) : "v"(x));
    return __int_as_float(__builtin_amdgcn_readlane(__float_as_int(x), 63));
}

// ---------------- preprocessing ----------------

__global__ void count_kernel(const int* __restrict__ dst, int* __restrict__ cnt, int E) {
    int t = blockIdx.x * blockDim.x + threadIdx.x;
    if (t >= E) return;
    atomicAdd(&cnt[dst[t]], 1);
}

// exclusive scan over (cnt[i]+1); also seeds winStart (folded win_start_kernel)
__global__ void scan_kernel(const int* __restrict__ cnt, int* __restrict__ offsets,
                            int* __restrict__ cursor, int* __restrict__ winStart, int N) {
    __shared__ int sums[1024];
    int t = threadIdx.x;
    int chunk = (N + 1023) / 1024;
    int beg = t * chunk;
    int end = min(beg + chunk, N);
    int s = 0;
    for (int i = beg; i < end; ++i) s += cnt[i] + 1;
    sums[t] = s;
    __syncthreads();
    for (int o = 1; o < 1024; o <<= 1) {
        int v = (t >= o) ? sums[t - o] : 0;
        __syncthreads();
        sums[t] += v;
        __syncthreads();
    }
    int run = (t > 0) ? sums[t - 1] : 0;
    for (int i = beg; i < end; ++i) {
        offsets[i] = run; cursor[i] = run;
        atomicMin(&winStart[run / CH], i);
        run += cnt[i] + 1;
    }
    if (t == 0) offsets[N] = sums[1023];
}

// CSR scatter + (folded reorder_ea): edge threads read their ea row (coalesced),
// convert fp32->fp16, and write easrt[pos] directly. recs[] eliminated.
// Self-loop threads record selfSlot; their easrt filled by loop_fill.
__global__ void scatter_kernel(const int* __restrict__ src, const int* __restrict__ dst,
                               const float* __restrict__ ea, int* __restrict__ cursor,
                               int* __restrict__ srcs, h2* __restrict__ easrt,
                               int* __restrict__ selfSlot, int N, int E) {
    int t = blockIdx.x * blockDim.x + threadIdx.x;
    if (t >= E + N) return;
    int d, s;
    if (t < E) { d = dst[t]; s = src[t]; }
    else       { d = t - E; s = t - E; }
    int pos = atomicAdd(&cursor[d], 1);
    srcs[pos] = s;
    if (t < E) {
        const float4* rp = (const float4*)(ea + (size_t)t * ED);
        float4 f0 = rp[0], f1 = rp[1], f2 = rp[2], f3 = rp[3];
        h2 o[8];
        o[0].x = (_Float16)f0.x; o[0].y = (_Float16)f0.y;
        o[1].x = (_Float16)f0.z; o[1].y = (_Float16)f0.w;
        o[2].x = (_Float16)f1.x; o[2].y = (_Float16)f1.y;
        o[3].x = (_Float16)f1.z; o[3].y = (_Float16)f1.w;
        o[4].x = (_Float16)f2.x; o[4].y = (_Float16)f2.y;
        o[5].x = (_Float16)f2.z; o[5].y = (_Float16)f2.w;
        o[6].x = (_Float16)f3.x; o[6].y = (_Float16)f3.y;
        o[7].x = (_Float16)f3.z; o[7].y = (_Float16)f3.w;
        float4* wp = (float4*)(easrt + (size_t)pos * 8);
        wp[0] = *(const float4*)&o[0];
        wp[1] = *(const float4*)&o[4];
    } else {
        selfSlot[d] = pos;
    }
}

// self-loop attr = mean of the segment's real-edge attrs, read SEQUENTIALLY from easrt
__global__ void loop_fill(const int* __restrict__ offsets, const int* __restrict__ selfSlot,
                          h2* __restrict__ easrt, int N) {
    int t = blockIdx.x * blockDim.x + threadIdx.x;
    int n = t >> 3, k2 = t & 7;
    if (n >= N) return;
    int beg = offsets[n], end = offsets[n + 1];
    int ss = selfSlot[n];
    float sx = 0.f, sy = 0.f;
    for (int j = beg; j < end; ++j) {
        if (j == ss) continue;
        h2 v = easrt[(size_t)j * 8 + k2];
        sx += (float)v.x; sy += (float)v.y;
    }
    float inv = 1.f / (float)max(end - beg - 1, 1);
    h2 o; o.x = (_Float16)(sx * inv); o.y = (_Float16)(sy * inv);
    easrt[(size_t)ss * 8 + k2] = o;
}

// all three W[K][320] -> Wt[320][K] fp16 transposes in one launch
__global__ void transpose_w3(const float* __restrict__ W0, const float* __restrict__ W12,
                             _Float16* __restrict__ Wt0, _Float16* __restrict__ Wt1,
                             _Float16* __restrict__ Wt2) {
    int t = blockIdx.x * blockDim.x + threadIdx.x;
    const int R0 = 320 * 128, R1 = 320 * 64;
    if (t < R0) {
        int k = t / 320, n = t % 320;
        Wt0[(size_t)n * 128 + k] = (_Float16)W0[t];
    } else if (t < R0 + R1) {
        int u = t - R0, k = u / 320, n = u % 320;
        Wt1[(size_t)n * 64 + k] = (_Float16)W12[u];
    } else if (t < R0 + 2 * R1) {
        int u = t - R0 - R1, k = u / 320, n = u % 320;
        Wt2[(size_t)n * 64 + k] = (_Float16)W12[64 * HC + u];
    }
}

// ---------------- MFMA GEMM: C = A[M,K] @ Wt[320,K]^T + bias ----------------
// A either fp16 (Ah) or fp32 (Af, converted in-register; layer 0 reads x directly).
// Split output: CoutA[row][64][4] = heads 0..3, CoutB[row][64] = head 4. 640 B/row.
__global__ __launch_bounds__(256) void gemm_mfma(const _Float16* __restrict__ Ah,
                                                 const float* __restrict__ Af,
                                                 const _Float16* __restrict__ Bt,
                                                 const float* __restrict__ bias,
                                                 _Float16* __restrict__ CoutA,
                                                 _Float16* __restrict__ CoutB, int M, int K) {
    int lane = threadIdx.x & 63;
    int wave = threadIdx.x >> 6;
    int m = lane & 15, quad = lane >> 4;
    int rowBase = (blockIdx.x * 4 + wave) * 16;
    if (rowBase >= M) return;

    v4f acc[20];
#pragma unroll
    for (int c = 0; c < 20; ++c) acc[c] = (v4f){0.f, 0.f, 0.f, 0.f};

    for (int k0 = 0; k0 < K; k0 += 32) {
        v8h a;
        if (Af) {
            const float* ap = &Af[(size_t)(rowBase + m) * K + k0 + quad * 8];
            float4 f0 = *(const float4*)ap;
            float4 f1 = *(const float4*)(ap + 4);
            a[0] = (_Float16)f0.x; a[1] = (_Float16)f0.y;
            a[2] = (_Float16)f0.z; a[3] = (_Float16)f0.w;
            a[4] = (_Float16)f1.x; a[5] = (_Float16)f1.y;
            a[6] = (_Float16)f1.z; a[7] = (_Float16)f1.w;
        } else {
            a = *(const v8h*)&Ah[(size_t)(rowBase + m) * K + k0 + quad * 8];
        }
#pragma unroll
        for (int c = 0; c < 20; ++c) {
            v8h b = *(const v8h*)&Bt[(size_t)(c * 16 + m) * K + k0 + quad * 8];
            acc[c] = __builtin_amdgcn_mfma_f32_16x16x32_f16(a, b, acc[c], 0, 0, 0);
        }
    }
    float bb[20];
#pragma unroll
    for (int c = 0; c < 20; ++c) bb[c] = bias[c * 16 + m];
#pragma unroll
    for (int r = 0; r < 4; ++r) {
        int row = rowBase + quad * 4 + r;
#pragma unroll
        for (int c03 = 0; c03 < 4; ++c03) {
            v4h o;
#pragma unroll
            for (int h = 0; h < 4; ++h) {
                int c = c03 + 4 * h;
                o[h] = (_Float16)(acc[c][r] + bb[c]);
            }
            int cw = c03 * 16 + m;
            *(v4h*)&CoutA[(((size_t)row) * 64 + cw) * 4] = o;
            int c4 = c03 + 16;                  // head 4
            CoutB[((size_t)row) * 64 + cw] = (_Float16)(acc[c4][r] + bb[c4]);
        }
    }
}

// ---------------- fused logits + single-pass softmax + aggregate + ELU ----------------
// Round-7 verbatim (proven 161 us, 4 passing runs).
__global__ __launch_bounds__(256) void gat_fused(const _Float16* __restrict__ hA,
                                                 const _Float16* __restrict__ hB,
                                                 const int* __restrict__ offsets,
                                                 const int* __restrict__ srcs,
                                                 const h2* __restrict__ easrt,
                                                 const int* __restrict__ winStart,
                                                 const float* __restrict__ We,
                                                 const float* __restrict__ att,
                                                 const float* __restrict__ bias,
                                                 _Float16* __restrict__ outH,
                                                 float* __restrict__ outF,
                                                 int N, int R) {
    int lane = threadIdx.x & 63;
    int wave = (blockIdx.x * blockDim.x + threadIdx.x) >> 6;
    int totalWaves = (gridDim.x * blockDim.x) >> 6;
    const float L2E = 1.4426950408889634f;   // fold log2(e) into att -> native v_exp (exp2)

    h2 we2[8 * NH];
#pragma unroll
    for (int k2 = 0; k2 < 8; ++k2)
#pragma unroll
        for (int h = 0; h < NH; ++h) {
            h2 w;
            w.x = (_Float16)We[(2 * k2) * HC + h * NC + lane];
            w.y = (_Float16)We[(2 * k2 + 1) * HC + h * NC + lane];
            we2[k2 * NH + h] = w;
        }
    float attc6[NH], attc4[NH];
#pragma unroll
    for (int h = 0; h < NH; ++h) {
        float a = att[h * NC + lane];
        attc6[h] = 0.6f * L2E * a;
        attc4[h] = 0.4f * L2E * a;
    }
    float bc = bias[lane];

    for (int w = wave; w * CH < R; w += totalWaves) {
        int i = winStart[w];
        if (i >= N) continue;
        int winEnd = w * CH + CH;
        for (; i < N; ++i) {
            int beg = offsets[i];
            if (beg >= winEnd) break;
            int end = offsets[i + 1];

            v4h hd4 = *(const v4h*)&hA[((size_t)i * 64 + lane) * 4];
            float hd[NH];
#pragma unroll
            for (int h = 0; h < 4; ++h) hd[h] = (float)hd4[h];
            hd[4] = (float)hB[(size_t)i * 64 + lane];

            float l[NH] = {}, acc[NH] = {};
            int t = beg;
            for (; t + 2 <= end; t += 2) {
                int s0 = srcs[t], s1 = srcs[t + 1];
                v4h hs0v = *(const v4h*)&hA[((size_t)s0 * 64 + lane) * 4];
                v4h hs1v = *(const v4h*)&hA[((size_t)s1 * 64 + lane) * 4];
                _Float16 hs0e = hB[(size_t)s0 * 64 + lane];
                _Float16 hs1e = hB[(size_t)s1 * 64 + lane];
                const h2* ap = easrt + (size_t)t * 8;
                h2 a0[8], a1[8];
#pragma unroll
                for (int k2 = 0; k2 < 8; ++k2) { a0[k2] = ap[k2]; a1[k2] = ap[8 + k2]; }
                __builtin_amdgcn_s_setprio(1);
                float hs0[NH], hs1[NH], p0[NH], p1[NH];
#pragma unroll
                for (int h = 0; h < 4; ++h) { hs0[h] = (float)hs0v[h]; hs1[h] = (float)hs1v[h]; }
                hs0[4] = (float)hs0e; hs1[4] = (float)hs1e;
#pragma unroll
                for (int h = 0; h < NH; ++h) {
                    float v0 = hs0[h] + hd[h];
                    float v1 = hs1[h] + hd[h];
#pragma unroll
                    for (int k2 = 0; k2 < 8; ++k2) {
                        v0 = __builtin_amdgcn_fdot2(a0[k2], we2[k2 * NH + h], v0, false);
                        v1 = __builtin_amdgcn_fdot2(a1[k2], we2[k2 * NH + h], v1, false);
                    }
                    p0[h] = fmaf(fabsf(v0), attc4[h], v0 * attc6[h]);
                    p1[h] = fmaf(fabsf(v1), attc4[h], v1 * attc6[h]);
                }
#pragma unroll
                for (int h = 0; h < NH; ++h) {
                    float pe0 = exp2f(wave_sum_all(p0[h]));
                    float pe1 = exp2f(wave_sum_all(p1[h]));
                    l[h] += pe0 + pe1;
                    acc[h] = fmaf(pe0, hs0[h], fmaf(pe1, hs1[h], acc[h]));
                }
                __builtin_amdgcn_s_setprio(0);
            }
            if (t < end) {
                int s0 = srcs[t];
                v4h hs0v = *(const v4h*)&hA[((size_t)s0 * 64 + lane) * 4];
                _Float16 hs0e = hB[(size_t)s0 * 64 + lane];
                const h2* ap = easrt + (size_t)t * 8;
                h2 a0[8];
#pragma unroll
                for (int k2 = 0; k2 < 8; ++k2) a0[k2] = ap[k2];
                float hs0[NH];
#pragma unroll
                for (int h = 0; h < 4; ++h) hs0[h] = (float)hs0v[h];
                hs0[4] = (float)hs0e;
#pragma unroll
                for (int h = 0; h < NH; ++h) {
                    float v0 = hs0[h] + hd[h];
#pragma unroll
                    for (int k2 = 0; k2 < 8; ++k2)
                        v0 = __builtin_amdgcn_fdot2(a0[k2], we2[k2 * NH + h], v0, false);
                    float pe0 = exp2f(wave_sum_all(fmaf(fabsf(v0), attc4[h], v0 * attc6[h])));
                    l[h] += pe0;
                    acc[h] = fmaf(pe0, hs0[h], acc[h]);
                }
            }
            float o = 0.f;
#pragma unroll
            for (int h = 0; h < NH; ++h) o += acc[h] / l[h];
            o = o * 0.2f + bc;
            o = o > 0.f ? o : expm1f(o);
            if (outF) outF[(size_t)i * NC + lane] = o;
            else      outH[(size_t)i * NC + lane] = (_Float16)o;
        }
    }
}

// ---------------- launch ----------------
extern "C" void kernel_launch(void* const* d_in, const int* in_sizes, int n_in,
                              void* d_out, int out_size, void* d_ws, size_t ws_size,
                              hipStream_t stream) {
    const float* x     = (const float*)d_in[0];
    const int*   ei    = (const int*)d_in[1];
    const float* ea    = (const float*)d_in[2];
    const float* W0    = (const float*)d_in[3];
    const float* b0    = (const float*)d_in[4];
    const float* We0   = (const float*)d_in[5];
    const float* att0  = (const float*)d_in[6];
    const float* bias0 = (const float*)d_in[7];
    const float* W12   = (const float*)d_in[8];
    const float* b12   = (const float*)d_in[9];
    const float* We12  = (const float*)d_in[10];
    const float* att12 = (const float*)d_in[11];
    const float* bias12= (const float*)d_in[12];

    int N = in_sizes[0] / 128;
    int E = in_sizes[1] / 2;
    int R = E + N;
    int numWin = (R + CH - 1) / CH;
    const int* srcArr = ei;
    const int* dstArr = ei + E;

    char* ws = (char*)d_ws;
    size_t off = 0;
    auto alloc = [&](size_t bytes) -> void* {
        void* p = ws + off;
        off = (off + bytes + 255) & ~(size_t)255;
        return p;
    };
    int*      cnt     = (int*)alloc((size_t)N * 4);
    int*      offsets = (int*)alloc((size_t)(N + 1) * 4);
    int*      cursor  = (int*)alloc((size_t)N * 4);
    int*      selfSlot= (int*)alloc((size_t)N * 4);
    _Float16* hbufA   = (_Float16*)alloc((size_t)N * 64 * 4 * 2); // [N][64][4] heads 0-3
    _Float16* hbufB   = (_Float16*)alloc((size_t)N * 64 * 2);     // [N][64]    head 4
    _Float16* acth    = (_Float16*)alloc((size_t)N * NC * 2);
    _Float16* Wth0    = (_Float16*)alloc((size_t)320 * 128 * 2);
    _Float16* Wth1    = (_Float16*)alloc((size_t)320 * 64 * 2);
    _Float16* Wth2    = (_Float16*)alloc((size_t)320 * 64 * 2);
    int*      winStart= (int*)alloc((size_t)(numWin + 1) * 4);
    h2*       easrt   = (h2*)alloc((size_t)R * 32);
    int*      srcs    = (int*)alloc((size_t)R * 4);

    (void)hipMemsetAsync(cnt, 0, (size_t)N * 4, stream);
    (void)hipMemsetAsync(winStart, 0x7f, (size_t)(numWin + 1) * 4, stream);
    count_kernel<<<(E + 255) / 256, 256, 0, stream>>>(dstArr, cnt, E);
    scan_kernel<<<1, 1024, 0, stream>>>(cnt, offsets, cursor, winStart, N);
    scatter_kernel<<<(E + N + 255) / 256, 256, 0, stream>>>(srcArr, dstArr, ea, cursor,
                                                            srcs, easrt, selfSlot, N, E);
    loop_fill<<<((size_t)N * 8 + 255) / 256, 256, 0, stream>>>(offsets, selfSlot, easrt, N);
    transpose_w3<<<(320 * 256 + 255) / 256, 256, 0, stream>>>(W0, W12, Wth0, Wth1, Wth2);

    float* dout = (float*)d_out;
    int gemmBlocks = (N / 16 + 3) / 4 + 1;
    int fusedBlocks = (numWin + 3) / 4;   // one window per wave

    const _Float16* Ahs[3] = {nullptr, acth, acth};
    const float*    Afs[3] = {x, nullptr, nullptr};
    const _Float16* Bts[3] = {Wth0, Wth1, Wth2};
    int Ks[3] = {128, 64, 64};
    const float* bs[3]   = {b0, b12, b12 + HC};
    const float* Wes[3]  = {We0, We12, We12 + ED * HC};
    const float* atts[3] = {att0, att12, att12 + NH * NC};
    const float* bis[3]  = {bias0, bias12, bias12 + NC};
    for (int layer = 0; layer < 3; ++layer) {
        gemm_mfma<<<gemmBlocks, 256, 0, stream>>>(Ahs[layer], Afs[layer], Bts[layer], bs[layer],
                                                  hbufA, hbufB, N, Ks[layer]);
        gat_fused<<<fusedBlocks, 256, 0, stream>>>(hbufA, hbufB, offsets, srcs, easrt, winStart,
                                                   Wes[layer], atts[layer], bis[layer],
                                                   acth, (layer == 2) ? dout : nullptr, N, R);
    }
}

// Round 9
// 809.677 us; speedup vs baseline: 1.1010x; 1.1010x over previous
//
#include <hip/hip_runtime.h>
#include <hip/hip_fp16.h>
#include <math.h>

#define NH 5
#define NC 64
#define ED 16
#define HC 320   // NH*NC
#define CH 32    // CSR slots per wave window in gat_fused

typedef _Float16 h2  __attribute__((ext_vector_type(2)));
typedef _Float16 v4h __attribute__((ext_vector_type(4)));
typedef _Float16 v8h __attribute__((ext_vector_type(8)));
typedef float    v4f __attribute__((ext_vector_type(4)));

// ---------------- wave64 sum via single-instruction DPP adds ----------------
// 10-chain interleave proven across 5 passing runs; do NOT widen (R5: 20 chains
// exposed the DPP read-after-VALU-write hazard the compiler can't see in asm).
__device__ __forceinline__ float wave_sum_all(float x) {
    asm("v_add_f32_dpp %0, %1, %0 quad_perm:[1,0,3,2] row_mask:0xf bank_mask:0xf"
        : "+v"(x) : "v"(x));
    asm("v_add_f32_dpp %0, %1, %0 quad_perm:[2,3,0,1] row_mask:0xf bank_mask:0xf"
        : "+v"(x) : "v"(x));
    asm("v_add_f32_dpp %0, %1, %0 row_half_mirror row_mask:0xf bank_mask:0xf"
        : "+v"(x) : "v"(x));
    asm("v_add_f32_dpp %0, %1, %0 row_mirror row_mask:0xf bank_mask:0xf"
        : "+v"(x) : "v"(x));
    asm("v_add_f32_dpp %0, %1, %0 row_bcast:15 row_mask:0xa bank_mask:0xf"
        : "+v"(x) : "v"(x));
    asm("v_add_f32_dpp %0, %1, %0 row_bcast:31 row_mask:0xc bank_mask:0xf"
        : "+v"(x) : "v"(x));
    return __int_as_float(__builtin_amdgcn_readlane(__float_as_int(x), 63));
}

// ---------------- preprocessing ----------------

__global__ void count_kernel(const int* __restrict__ dst, int* __restrict__ cnt, int E) {
    int t = blockIdx.x * blockDim.x + threadIdx.x;
    if (t >= E) return;
    atomicAdd(&cnt[dst[t]], 1);
}

// exclusive scan over (cnt[i]+1). NO winStart seeding here: 50k atomics from a
// single block serialize on one CU (R8: scan 216 us). Parallel kernel instead.
__global__ void scan_kernel(const int* __restrict__ cnt, int* __restrict__ offsets,
                            int* __restrict__ cursor, int N) {
    __shared__ int sums[1024];
    int t = threadIdx.x;
    int chunk = (N + 1023) / 1024;
    int beg = t * chunk;
    int end = min(beg + chunk, N);
    int s = 0;
    for (int i = beg; i < end; ++i) s += cnt[i] + 1;
    sums[t] = s;
    __syncthreads();
    for (int o = 1; o < 1024; o <<= 1) {
        int v = (t >= o) ? sums[t - o] : 0;
        __syncthreads();
        sums[t] += v;
        __syncthreads();
    }
    int run = (t > 0) ? sums[t - 1] : 0;
    for (int i = beg; i < end; ++i) {
        offsets[i] = run; cursor[i] = run;
        run += cnt[i] + 1;
    }
    if (t == 0) offsets[N] = sums[1023];
}

// window -> first node starting in it (atomicMin; sentinel 0x7f7f7f7f)
__global__ void win_start_kernel(const int* __restrict__ offsets, int* __restrict__ winStart, int N) {
    int i = blockIdx.x * blockDim.x + threadIdx.x;
    if (i >= N) return;
    atomicMin(&winStart[offsets[i] / CH], i);
}

// CSR scatter + folded reorder_ea: edge threads read their ea row (coalesced),
// convert fp32->fp16, write easrt[pos] directly. recs[] eliminated.
__global__ void scatter_kernel(const int* __restrict__ src, const int* __restrict__ dst,
                               const float* __restrict__ ea, int* __restrict__ cursor,
                               int* __restrict__ srcs, h2* __restrict__ easrt,
                               int* __restrict__ selfSlot, int N, int E) {
    int t = blockIdx.x * blockDim.x + threadIdx.x;
    if (t >= E + N) return;
    int d, s;
    if (t < E) { d = dst[t]; s = src[t]; }
    else       { d = t - E; s = t - E; }
    int pos = atomicAdd(&cursor[d], 1);
    srcs[pos] = s;
    if (t < E) {
        const float4* rp = (const float4*)(ea + (size_t)t * ED);
        float4 f0 = rp[0], f1 = rp[1], f2 = rp[2], f3 = rp[3];
        h2 o[8];
        o[0].x = (_Float16)f0.x; o[0].y = (_Float16)f0.y;
        o[1].x = (_Float16)f0.z; o[1].y = (_Float16)f0.w;
        o[2].x = (_Float16)f1.x; o[2].y = (_Float16)f1.y;
        o[3].x = (_Float16)f1.z; o[3].y = (_Float16)f1.w;
        o[4].x = (_Float16)f2.x; o[4].y = (_Float16)f2.y;
        o[5].x = (_Float16)f2.z; o[5].y = (_Float16)f2.w;
        o[6].x = (_Float16)f3.x; o[6].y = (_Float16)f3.y;
        o[7].x = (_Float16)f3.z; o[7].y = (_Float16)f3.w;
        float4* wp = (float4*)(easrt + (size_t)pos * 8);
        wp[0] = *(const float4*)&o[0];
        wp[1] = *(const float4*)&o[4];
    } else {
        selfSlot[d] = pos;
    }
}

// self-loop attr = mean of the segment's real-edge attrs, read SEQUENTIALLY from easrt
__global__ void loop_fill(const int* __restrict__ offsets, const int* __restrict__ selfSlot,
                          h2* __restrict__ easrt, int N) {
    int t = blockIdx.x * blockDim.x + threadIdx.x;
    int n = t >> 3, k2 = t & 7;
    if (n >= N) return;
    int beg = offsets[n], end = offsets[n + 1];
    int ss = selfSlot[n];
    float sx = 0.f, sy = 0.f;
    for (int j = beg; j < end; ++j) {
        if (j == ss) continue;
        h2 v = easrt[(size_t)j * 8 + k2];
        sx += (float)v.x; sy += (float)v.y;
    }
    float inv = 1.f / (float)max(end - beg - 1, 1);
    h2 o; o.x = (_Float16)(sx * inv); o.y = (_Float16)(sy * inv);
    easrt[(size_t)ss * 8 + k2] = o;
}

// all three W[K][320] -> Wt[320][K] fp16 transposes in one launch
__global__ void transpose_w3(const float* __restrict__ W0, const float* __restrict__ W12,
                             _Float16* __restrict__ Wt0, _Float16* __restrict__ Wt1,
                             _Float16* __restrict__ Wt2) {
    int t = blockIdx.x * blockDim.x + threadIdx.x;
    const int R0 = 320 * 128, R1 = 320 * 64;
    if (t < R0) {
        int k = t / 320, n = t % 320;
        Wt0[(size_t)n * 128 + k] = (_Float16)W0[t];
    } else if (t < R0 + R1) {
        int u = t - R0, k = u / 320, n = u % 320;
        Wt1[(size_t)n * 64 + k] = (_Float16)W12[u];
    } else if (t < R0 + 2 * R1) {
        int u = t - R0 - R1, k = u / 320, n = u % 320;
        Wt2[(size_t)n * 64 + k] = (_Float16)W12[64 * HC + u];
    }
}

// ---------------- MFMA GEMM: C = A[M,K] @ Wt[320,K]^T + bias ----------------
// A either fp16 (Ah) or fp32 (Af, converted in-register; layer 0 reads x directly).
// Split output: CoutA[row][64][4] = heads 0..3, CoutB[row][64] = head 4. 640 B/row.
__global__ __launch_bounds__(256) void gemm_mfma(const _Float16* __restrict__ Ah,
                                                 const float* __restrict__ Af,
                                                 const _Float16* __restrict__ Bt,
                                                 const float* __restrict__ bias,
                                                 _Float16* __restrict__ CoutA,
                                                 _Float16* __restrict__ CoutB, int M, int K) {
    int lane = threadIdx.x & 63;
    int wave = threadIdx.x >> 6;
    int m = lane & 15, quad = lane >> 4;
    int rowBase = (blockIdx.x * 4 + wave) * 16;
    if (rowBase >= M) return;

    v4f acc[20];
#pragma unroll
    for (int c = 0; c < 20; ++c) acc[c] = (v4f){0.f, 0.f, 0.f, 0.f};

    for (int k0 = 0; k0 < K; k0 += 32) {
        v8h a;
        if (Af) {
            const float* ap = &Af[(size_t)(rowBase + m) * K + k0 + quad * 8];
            float4 f0 = *(const float4*)ap;
            float4 f1 = *(const float4*)(ap + 4);
            a[0] = (_Float16)f0.x; a[1] = (_Float16)f0.y;
            a[2] = (_Float16)f0.z; a[3] = (_Float16)f0.w;
            a[4] = (_Float16)f1.x; a[5] = (_Float16)f1.y;
            a[6] = (_Float16)f1.z; a[7] = (_Float16)f1.w;
        } else {
            a = *(const v8h*)&Ah[(size_t)(rowBase + m) * K + k0 + quad * 8];
        }
#pragma unroll
        for (int c = 0; c < 20; ++c) {
            v8h b = *(const v8h*)&Bt[(size_t)(c * 16 + m) * K + k0 + quad * 8];
            acc[c] = __builtin_amdgcn_mfma_f32_16x16x32_f16(a, b, acc[c], 0, 0, 0);
        }
    }
    float bb[20];
#pragma unroll
    for (int c = 0; c < 20; ++c) bb[c] = bias[c * 16 + m];
#pragma unroll
    for (int r = 0; r < 4; ++r) {
        int row = rowBase + quad * 4 + r;
#pragma unroll
        for (int c03 = 0; c03 < 4; ++c03) {
            v4h o;
#pragma unroll
            for (int h = 0; h < 4; ++h) {
                int c = c03 + 4 * h;
                o[h] = (_Float16)(acc[c][r] + bb[c]);
            }
            int cw = c03 * 16 + m;
            *(v4h*)&CoutA[(((size_t)row) * 64 + cw) * 4] = o;
            int c4 = c03 + 16;                  // head 4
            CoutB[((size_t)row) * 64 + cw] = (_Float16)(acc[c4][r] + bb[c4]);
        }
    }
}

// ---------------- fused logits + single-pass softmax + aggregate + ELU ----------------
// Round-7 verbatim (proven 161 us, 5 passing runs).
__global__ __launch_bounds__(256) void gat_fused(const _Float16* __restrict__ hA,
                                                 const _Float16* __restrict__ hB,
                                                 const int* __restrict__ offsets,
                                                 const int* __restrict__ srcs,
                                                 const h2* __restrict__ easrt,
                                                 const int* __restrict__ winStart,
                                                 const float* __restrict__ We,
                                                 const float* __restrict__ att,
                                                 const float* __restrict__ bias,
                                                 _Float16* __restrict__ outH,
                                                 float* __restrict__ outF,
                                                 int N, int R) {
    int lane = threadIdx.x & 63;
    int wave = (blockIdx.x * blockDim.x + threadIdx.x) >> 6;
    int totalWaves = (gridDim.x * blockDim.x) >> 6;
    const float L2E = 1.4426950408889634f;   // fold log2(e) into att -> native v_exp (exp2)

    h2 we2[8 * NH];
#pragma unroll
    for (int k2 = 0; k2 < 8; ++k2)
#pragma unroll
        for (int h = 0; h < NH; ++h) {
            h2 w;
            w.x = (_Float16)We[(2 * k2) * HC + h * NC + lane];
            w.y = (_Float16)We[(2 * k2 + 1) * HC + h * NC + lane];
            we2[k2 * NH + h] = w;
        }
    float attc6[NH], attc4[NH];
#pragma unroll
    for (int h = 0; h < NH; ++h) {
        float a = att[h * NC + lane];
        attc6[h] = 0.6f * L2E * a;
        attc4[h] = 0.4f * L2E * a;
    }
    float bc = bias[lane];

    for (int w = wave; w * CH < R; w += totalWaves) {
        int i = winStart[w];
        if (i >= N) continue;
        int winEnd = w * CH + CH;
        for (; i < N; ++i) {
            int beg = offsets[i];
            if (beg >= winEnd) break;
            int end = offsets[i + 1];

            v4h hd4 = *(const v4h*)&hA[((size_t)i * 64 + lane) * 4];
            float hd[NH];
#pragma unroll
            for (int h = 0; h < 4; ++h) hd[h] = (float)hd4[h];
            hd[4] = (float)hB[(size_t)i * 64 + lane];

            float l[NH] = {}, acc[NH] = {};
            int t = beg;
            for (; t + 2 <= end; t += 2) {
                int s0 = srcs[t], s1 = srcs[t + 1];
                v4h hs0v = *(const v4h*)&hA[((size_t)s0 * 64 + lane) * 4];
                v4h hs1v = *(const v4h*)&hA[((size_t)s1 * 64 + lane) * 4];
                _Float16 hs0e = hB[(size_t)s0 * 64 + lane];
                _Float16 hs1e = hB[(size_t)s1 * 64 + lane];
                const h2* ap = easrt + (size_t)t * 8;
                h2 a0[8], a1[8];
#pragma unroll
                for (int k2 = 0; k2 < 8; ++k2) { a0[k2] = ap[k2]; a1[k2] = ap[8 + k2]; }
                __builtin_amdgcn_s_setprio(1);
                float hs0[NH], hs1[NH], p0[NH], p1[NH];
#pragma unroll
                for (int h = 0; h < 4; ++h) { hs0[h] = (float)hs0v[h]; hs1[h] = (float)hs1v[h]; }
                hs0[4] = (float)hs0e; hs1[4] = (float)hs1e;
#pragma unroll
                for (int h = 0; h < NH; ++h) {
                    float v0 = hs0[h] + hd[h];
                    float v1 = hs1[h] + hd[h];
#pragma unroll
                    for (int k2 = 0; k2 < 8; ++k2) {
                        v0 = __builtin_amdgcn_fdot2(a0[k2], we2[k2 * NH + h], v0, false);
                        v1 = __builtin_amdgcn_fdot2(a1[k2], we2[k2 * NH + h], v1, false);
                    }
                    p0[h] = fmaf(fabsf(v0), attc4[h], v0 * attc6[h]);
                    p1[h] = fmaf(fabsf(v1), attc4[h], v1 * attc6[h]);
                }
#pragma unroll
                for (int h = 0; h < NH; ++h) {
                    float pe0 = exp2f(wave_sum_all(p0[h]));
                    float pe1 = exp2f(wave_sum_all(p1[h]));
                    l[h] += pe0 + pe1;
                    acc[h] = fmaf(pe0, hs0[h], fmaf(pe1, hs1[h], acc[h]));
                }
                __builtin_amdgcn_s_setprio(0);
            }
            if (t < end) {
                int s0 = srcs[t];
                v4h hs0v = *(const v4h*)&hA[((size_t)s0 * 64 + lane) * 4];
                _Float16 hs0e = hB[(size_t)s0 * 64 + lane];
                const h2* ap = easrt + (size_t)t * 8;
                h2 a0[8];
#pragma unroll
                for (int k2 = 0; k2 < 8; ++k2) a0[k2] = ap[k2];
                float hs0[NH];
#pragma unroll
                for (int h = 0; h < 4; ++h) hs0[h] = (float)hs0v[h];
                hs0[4] = (float)hs0e;
#pragma unroll
                for (int h = 0; h < NH; ++h) {
                    float v0 = hs0[h] + hd[h];
#pragma unroll
                    for (int k2 = 0; k2 < 8; ++k2)
                        v0 = __builtin_amdgcn_fdot2(a0[k2], we2[k2 * NH + h], v0, false);
                    float pe0 = exp2f(wave_sum_all(fmaf(fabsf(v0), attc4[h], v0 * attc6[h])));
                    l[h] += pe0;
                    acc[h] = fmaf(pe0, hs0[h], acc[h]);
                }
            }
            float o = 0.f;
#pragma unroll
            for (int h = 0; h < NH; ++h) o += acc[h] / l[h];
            o = o * 0.2f + bc;
            o = o > 0.f ? o : expm1f(o);
            if (outF) outF[(size_t)i * NC + lane] = o;
            else      outH[(size_t)i * NC + lane] = (_Float16)o;
        }
    }
}

// ---------------- launch ----------------
extern "C" void kernel_launch(void* const* d_in, const int* in_sizes, int n_in,
                              void* d_out, int out_size, void* d_ws, size_t ws_size,
                              hipStream_t stream) {
    const float* x     = (const float*)d_in[0];
    const int*   ei    = (const int*)d_in[1];
    const float* ea    = (const float*)d_in[2];
    const float* W0    = (const float*)d_in[3];
    const float* b0    = (const float*)d_in[4];
    const float* We0   = (const float*)d_in[5];
    const float* att0  = (const float*)d_in[6];
    const float* bias0 = (const float*)d_in[7];
    const float* W12   = (const float*)d_in[8];
    const float* b12   = (const float*)d_in[9];
    const float* We12  = (const float*)d_in[10];
    const float* att12 = (const float*)d_in[11];
    const float* bias12= (const float*)d_in[12];

    int N = in_sizes[0] / 128;
    int E = in_sizes[1] / 2;
    int R = E + N;
    int numWin = (R + CH - 1) / CH;
    const int* srcArr = ei;
    const int* dstArr = ei + E;

    char* ws = (char*)d_ws;
    size_t off = 0;
    auto alloc = [&](size_t bytes) -> void* {
        void* p = ws + off;
        off = (off + bytes + 255) & ~(size_t)255;
        return p;
    };
    int*      cnt     = (int*)alloc((size_t)N * 4);
    int*      offsets = (int*)alloc((size_t)(N + 1) * 4);
    int*      cursor  = (int*)alloc((size_t)N * 4);
    int*      selfSlot= (int*)alloc((size_t)N * 4);
    _Float16* hbufA   = (_Float16*)alloc((size_t)N * 64 * 4 * 2); // [N][64][4] heads 0-3
    _Float16* hbufB   = (_Float16*)alloc((size_t)N * 64 * 2);     // [N][64]    head 4
    _Float16* acth    = (_Float16*)alloc((size_t)N * NC * 2);
    _Float16* Wth0    = (_Float16*)alloc((size_t)320 * 128 * 2);
    _Float16* Wth1    = (_Float16*)alloc((size_t)320 * 64 * 2);
    _Float16* Wth2    = (_Float16*)alloc((size_t)320 * 64 * 2);
    int*      winStart= (int*)alloc((size_t)(numWin + 1) * 4);
    h2*       easrt   = (h2*)alloc((size_t)R * 32);
    int*      srcs    = (int*)alloc((size_t)R * 4);

    (void)hipMemsetAsync(cnt, 0, (size_t)N * 4, stream);
    (void)hipMemsetAsync(winStart, 0x7f, (size_t)(numWin + 1) * 4, stream);
    count_kernel<<<(E + 255) / 256, 256, 0, stream>>>(dstArr, cnt, E);
    scan_kernel<<<1, 1024, 0, stream>>>(cnt, offsets, cursor, N);
    win_start_kernel<<<(N + 255) / 256, 256, 0, stream>>>(offsets, winStart, N);
    scatter_kernel<<<(E + N + 255) / 256, 256, 0, stream>>>(srcArr, dstArr, ea, cursor,
                                                            srcs, easrt, selfSlot, N, E);
    loop_fill<<<((size_t)N * 8 + 255) / 256, 256, 0, stream>>>(offsets, selfSlot, easrt, N);
    transpose_w3<<<(320 * 256 + 255) / 256, 256, 0, stream>>>(W0, W12, Wth0, Wth1, Wth2);

    float* dout = (float*)d_out;
    int gemmBlocks = (N / 16 + 3) / 4 + 1;
    int fusedBlocks = (numWin + 3) / 4;   // one window per wave

    const _Float16* Ahs[3] = {nullptr, acth, acth};
    const float*    Afs[3] = {x, nullptr, nullptr};
    const _Float16* Bts[3] = {Wth0, Wth1, Wth2};
    int Ks[3] = {128, 64, 64};
    const float* bs[3]   = {b0, b12, b12 + HC};
    const float* Wes[3]  = {We0, We12, We12 + ED * HC};
    const float* atts[3] = {att0, att12, att12 + NH * NC};
    const float* bis[3]  = {bias0, bias12, bias12 + NC};
    for (int layer = 0; layer < 3; ++layer) {
        gemm_mfma<<<gemmBlocks, 256, 0, stream>>>(Ahs[layer], Afs[layer], Bts[layer], bs[layer],
                                                  hbufA, hbufB, N, Ks[layer]);
        gat_fused<<<fusedBlocks, 256, 0, stream>>>(hbufA, hbufB, offsets, srcs, easrt, winStart,
                                                   Wes[layer], atts[layer], bis[layer],
                                                   acth, (layer == 2) ? dout : nullptr, N, R);
    }
}

// Round 10
// 714.405 us; speedup vs baseline: 1.2478x; 1.1334x over previous
//
#include <hip/hip_runtime.h>
#include <hip/hip_fp16.h>
#include <math.h>

#define NH 5
#define NC 64
#define ED 16
#define HC 320   // NH*NC
#define CH 32    // CSR slots per wave window in gat_fused

typedef _Float16 h2  __attribute__((ext_vector_type(2)));
typedef _Float16 v4h __attribute__((ext_vector_type(4)));
typedef _Float16 v8h __attribute__((ext_vector_type(8)));
typedef float    v4f __attribute__((ext_vector_type(4)));

// ---------------- wave64 sum via single-instruction DPP adds ----------------
// 10-chain interleave proven across 6 passing runs; do NOT widen (R5: 20 chains
// exposed the DPP read-after-VALU-write hazard the compiler can't see in asm).
__device__ __forceinline__ float wave_sum_all(float x) {
    asm("v_add_f32_dpp %0, %1, %0 quad_perm:[1,0,3,2] row_mask:0xf bank_mask:0xf"
        : "+v"(x) : "v"(x));
    asm("v_add_f32_dpp %0, %1, %0 quad_perm:[2,3,0,1] row_mask:0xf bank_mask:0xf"
        : "+v"(x) : "v"(x));
    asm("v_add_f32_dpp %0, %1, %0 row_half_mirror row_mask:0xf bank_mask:0xf"
        : "+v"(x) : "v"(x));
    asm("v_add_f32_dpp %0, %1, %0 row_mirror row_mask:0xf bank_mask:0xf"
        : "+v"(x) : "v"(x));
    asm("v_add_f32_dpp %0, %1, %0 row_bcast:15 row_mask:0xa bank_mask:0xf"
        : "+v"(x) : "v"(x));
    asm("v_add_f32_dpp %0, %1, %0 row_bcast:31 row_mask:0xc bank_mask:0xf"
        : "+v"(x) : "v"(x));
    return __int_as_float(__builtin_amdgcn_readlane(__float_as_int(x), 63));
}

// ---------------- preprocessing ----------------

__global__ void count_kernel(const int* __restrict__ dst, int* __restrict__ cnt, int E) {
    int t = blockIdx.x * blockDim.x + threadIdx.x;
    if (t >= E) return;
    atomicAdd(&cnt[dst[t]], 1);
}

// ---- parallel 3-phase scan over v[i] = cnt[i]+1 (replaces 135us 1-block scan) ----
// scan1: per-block LDS Hillis-Steele; offsets[i] = exclusive prefix within block
__global__ void scan1_kernel(const int* __restrict__ cnt, int* __restrict__ offsets,
                             int* __restrict__ blockSums, int N) {
    __shared__ int sh[1024];
    int i = blockIdx.x * 1024 + threadIdx.x;
    int v = (i < N) ? cnt[i] + 1 : 0;
    sh[threadIdx.x] = v;
    __syncthreads();
    for (int o = 1; o < 1024; o <<= 1) {
        int t = (threadIdx.x >= o) ? sh[threadIdx.x - o] : 0;
        __syncthreads();
        sh[threadIdx.x] += t;
        __syncthreads();
    }
    if (i < N) offsets[i] = sh[threadIdx.x] - v;   // exclusive
    if (threadIdx.x == 1023) blockSums[blockIdx.x] = sh[1023];
}

// scan2: serial exclusive scan of ~49 block sums; blockSums[nb] = grand total
__global__ void scan2_kernel(int* __restrict__ blockSums, int nb) {
    if (threadIdx.x != 0 || blockIdx.x != 0) return;
    int run = 0;
    for (int j = 0; j < nb; ++j) {
        int v = blockSums[j];
        blockSums[j] = run;
        run += v;
    }
    blockSums[nb] = run;
}

// scan3: add block base; write cursor; seed winStart (parallel grid -> atomics cheap,
// unlike R8's single-block fold); offsets[N] = total
__global__ void scan3_kernel(int* __restrict__ offsets, int* __restrict__ cursor,
                             const int* __restrict__ blockSums, int* __restrict__ winStart,
                             int N, int nb) {
    int i = blockIdx.x * blockDim.x + threadIdx.x;
    if (i >= N) return;
    int off = offsets[i] + blockSums[i >> 10];
    offsets[i] = off;
    cursor[i] = off;
    atomicMin(&winStart[off / CH], i);
    if (i == 0) offsets[N] = blockSums[nb];
}

// CSR scatter + folded reorder_ea: edge threads read their ea row (coalesced),
// convert fp32->fp16, write easrt[pos] directly. recs[] eliminated.
__global__ void scatter_kernel(const int* __restrict__ src, const int* __restrict__ dst,
                               const float* __restrict__ ea, int* __restrict__ cursor,
                               int* __restrict__ srcs, h2* __restrict__ easrt,
                               int* __restrict__ selfSlot, int N, int E) {
    int t = blockIdx.x * blockDim.x + threadIdx.x;
    if (t >= E + N) return;
    int d, s;
    if (t < E) { d = dst[t]; s = src[t]; }
    else       { d = t - E; s = t - E; }
    int pos = atomicAdd(&cursor[d], 1);
    srcs[pos] = s;
    if (t < E) {
        const float4* rp = (const float4*)(ea + (size_t)t * ED);
        float4 f0 = rp[0], f1 = rp[1], f2 = rp[2], f3 = rp[3];
        h2 o[8];
        o[0].x = (_Float16)f0.x; o[0].y = (_Float16)f0.y;
        o[1].x = (_Float16)f0.z; o[1].y = (_Float16)f0.w;
        o[2].x = (_Float16)f1.x; o[2].y = (_Float16)f1.y;
        o[3].x = (_Float16)f1.z; o[3].y = (_Float16)f1.w;
        o[4].x = (_Float16)f2.x; o[4].y = (_Float16)f2.y;
        o[5].x = (_Float16)f2.z; o[5].y = (_Float16)f2.w;
        o[6].x = (_Float16)f3.x; o[6].y = (_Float16)f3.y;
        o[7].x = (_Float16)f3.z; o[7].y = (_Float16)f3.w;
        float4* wp = (float4*)(easrt + (size_t)pos * 8);
        wp[0] = *(const float4*)&o[0];
        wp[1] = *(const float4*)&o[4];
    } else {
        selfSlot[d] = pos;
    }
}

// self-loop attr = mean of the segment's real-edge attrs, read SEQUENTIALLY from easrt
__global__ void loop_fill(const int* __restrict__ offsets, const int* __restrict__ selfSlot,
                          h2* __restrict__ easrt, int N) {
    int t = blockIdx.x * blockDim.x + threadIdx.x;
    int n = t >> 3, k2 = t & 7;
    if (n >= N) return;
    int beg = offsets[n], end = offsets[n + 1];
    int ss = selfSlot[n];
    float sx = 0.f, sy = 0.f;
    for (int j = beg; j < end; ++j) {
        if (j == ss) continue;
        h2 v = easrt[(size_t)j * 8 + k2];
        sx += (float)v.x; sy += (float)v.y;
    }
    float inv = 1.f / (float)max(end - beg - 1, 1);
    h2 o; o.x = (_Float16)(sx * inv); o.y = (_Float16)(sy * inv);
    easrt[(size_t)ss * 8 + k2] = o;
}

// all three W[K][320] -> Wt[320][K] fp16 transposes in one launch
__global__ void transpose_w3(const float* __restrict__ W0, const float* __restrict__ W12,
                             _Float16* __restrict__ Wt0, _Float16* __restrict__ Wt1,
                             _Float16* __restrict__ Wt2) {
    int t = blockIdx.x * blockDim.x + threadIdx.x;
    const int R0 = 320 * 128, R1 = 320 * 64;
    if (t < R0) {
        int k = t / 320, n = t % 320;
        Wt0[(size_t)n * 128 + k] = (_Float16)W0[t];
    } else if (t < R0 + R1) {
        int u = t - R0, k = u / 320, n = u % 320;
        Wt1[(size_t)n * 64 + k] = (_Float16)W12[u];
    } else if (t < R0 + 2 * R1) {
        int u = t - R0 - R1, k = u / 320, n = u % 320;
        Wt2[(size_t)n * 64 + k] = (_Float16)W12[64 * HC + u];
    }
}

// ---------------- MFMA GEMM: C = A[M,K] @ Wt[320,K]^T + bias ----------------
// A either fp16 (Ah) or fp32 (Af, converted in-register; layer 0 reads x directly).
// Split output: CoutA[row][64][4] = heads 0..3, CoutB[row][64] = head 4. 640 B/row.
__global__ __launch_bounds__(256) void gemm_mfma(const _Float16* __restrict__ Ah,
                                                 const float* __restrict__ Af,
                                                 const _Float16* __restrict__ Bt,
                                                 const float* __restrict__ bias,
                                                 _Float16* __restrict__ CoutA,
                                                 _Float16* __restrict__ CoutB, int M, int K) {
    int lane = threadIdx.x & 63;
    int wave = threadIdx.x >> 6;
    int m = lane & 15, quad = lane >> 4;
    int rowBase = (blockIdx.x * 4 + wave) * 16;
    if (rowBase >= M) return;

    v4f acc[20];
#pragma unroll
    for (int c = 0; c < 20; ++c) acc[c] = (v4f){0.f, 0.f, 0.f, 0.f};

    for (int k0 = 0; k0 < K; k0 += 32) {
        v8h a;
        if (Af) {
            const float* ap = &Af[(size_t)(rowBase + m) * K + k0 + quad * 8];
            float4 f0 = *(const float4*)ap;
            float4 f1 = *(const float4*)(ap + 4);
            a[0] = (_Float16)f0.x; a[1] = (_Float16)f0.y;
            a[2] = (_Float16)f0.z; a[3] = (_Float16)f0.w;
            a[4] = (_Float16)f1.x; a[5] = (_Float16)f1.y;
            a[6] = (_Float16)f1.z; a[7] = (_Float16)f1.w;
        } else {
            a = *(const v8h*)&Ah[(size_t)(rowBase + m) * K + k0 + quad * 8];
        }
#pragma unroll
        for (int c = 0; c < 20; ++c) {
            v8h b = *(const v8h*)&Bt[(size_t)(c * 16 + m) * K + k0 + quad * 8];
            acc[c] = __builtin_amdgcn_mfma_f32_16x16x32_f16(a, b, acc[c], 0, 0, 0);
        }
    }
    float bb[20];
#pragma unroll
    for (int c = 0; c < 20; ++c) bb[c] = bias[c * 16 + m];
#pragma unroll
    for (int r = 0; r < 4; ++r) {
        int row = rowBase + quad * 4 + r;
#pragma unroll
        for (int c03 = 0; c03 < 4; ++c03) {
            v4h o;
#pragma unroll
            for (int h = 0; h < 4; ++h) {
                int c = c03 + 4 * h;
                o[h] = (_Float16)(acc[c][r] + bb[c]);
            }
            int cw = c03 * 16 + m;
            *(v4h*)&CoutA[(((size_t)row) * 64 + cw) * 4] = o;
            int c4 = c03 + 16;                  // head 4
            CoutB[((size_t)row) * 64 + cw] = (_Float16)(acc[c4][r] + bb[c4]);
        }
    }
}

// ---------------- fused logits + single-pass softmax + aggregate + ELU ----------------
// Round-7 verbatim (proven ~160 us, 6 passing runs).
__global__ __launch_bounds__(256) void gat_fused(const _Float16* __restrict__ hA,
                                                 const _Float16* __restrict__ hB,
                                                 const int* __restrict__ offsets,
                                                 const int* __restrict__ srcs,
                                                 const h2* __restrict__ easrt,
                                                 const int* __restrict__ winStart,
                                                 const float* __restrict__ We,
                                                 const float* __restrict__ att,
                                                 const float* __restrict__ bias,
                                                 _Float16* __restrict__ outH,
                                                 float* __restrict__ outF,
                                                 int N, int R) {
    int lane = threadIdx.x & 63;
    int wave = (blockIdx.x * blockDim.x + threadIdx.x) >> 6;
    int totalWaves = (gridDim.x * blockDim.x) >> 6;
    const float L2E = 1.4426950408889634f;   // fold log2(e) into att -> native v_exp (exp2)

    h2 we2[8 * NH];
#pragma unroll
    for (int k2 = 0; k2 < 8; ++k2)
#pragma unroll
        for (int h = 0; h < NH; ++h) {
            h2 w;
            w.x = (_Float16)We[(2 * k2) * HC + h * NC + lane];
            w.y = (_Float16)We[(2 * k2 + 1) * HC + h * NC + lane];
            we2[k2 * NH + h] = w;
        }
    float attc6[NH], attc4[NH];
#pragma unroll
    for (int h = 0; h < NH; ++h) {
        float a = att[h * NC + lane];
        attc6[h] = 0.6f * L2E * a;
        attc4[h] = 0.4f * L2E * a;
    }
    float bc = bias[lane];

    for (int w = wave; w * CH < R; w += totalWaves) {
        int i = winStart[w];
        if (i >= N) continue;
        int winEnd = w * CH + CH;
        for (; i < N; ++i) {
            int beg = offsets[i];
            if (beg >= winEnd) break;
            int end = offsets[i + 1];

            v4h hd4 = *(const v4h*)&hA[((size_t)i * 64 + lane) * 4];
            float hd[NH];
#pragma unroll
            for (int h = 0; h < 4; ++h) hd[h] = (float)hd4[h];
            hd[4] = (float)hB[(size_t)i * 64 + lane];

            float l[NH] = {}, acc[NH] = {};
            int t = beg;
            for (; t + 2 <= end; t += 2) {
                int s0 = srcs[t], s1 = srcs[t + 1];
                v4h hs0v = *(const v4h*)&hA[((size_t)s0 * 64 + lane) * 4];
                v4h hs1v = *(const v4h*)&hA[((size_t)s1 * 64 + lane) * 4];
                _Float16 hs0e = hB[(size_t)s0 * 64 + lane];
                _Float16 hs1e = hB[(size_t)s1 * 64 + lane];
                const h2* ap = easrt + (size_t)t * 8;
                h2 a0[8], a1[8];
#pragma unroll
                for (int k2 = 0; k2 < 8; ++k2) { a0[k2] = ap[k2]; a1[k2] = ap[8 + k2]; }
                __builtin_amdgcn_s_setprio(1);
                float hs0[NH], hs1[NH], p0[NH], p1[NH];
#pragma unroll
                for (int h = 0; h < 4; ++h) { hs0[h] = (float)hs0v[h]; hs1[h] = (float)hs1v[h]; }
                hs0[4] = (float)hs0e; hs1[4] = (float)hs1e;
#pragma unroll
                for (int h = 0; h < NH; ++h) {
                    float v0 = hs0[h] + hd[h];
                    float v1 = hs1[h] + hd[h];
#pragma unroll
                    for (int k2 = 0; k2 < 8; ++k2) {
                        v0 = __builtin_amdgcn_fdot2(a0[k2], we2[k2 * NH + h], v0, false);
                        v1 = __builtin_amdgcn_fdot2(a1[k2], we2[k2 * NH + h], v1, false);
                    }
                    p0[h] = fmaf(fabsf(v0), attc4[h], v0 * attc6[h]);
                    p1[h] = fmaf(fabsf(v1), attc4[h], v1 * attc6[h]);
                }
#pragma unroll
                for (int h = 0; h < NH; ++h) {
                    float pe0 = exp2f(wave_sum_all(p0[h]));
                    float pe1 = exp2f(wave_sum_all(p1[h]));
                    l[h] += pe0 + pe1;
                    acc[h] = fmaf(pe0, hs0[h], fmaf(pe1, hs1[h], acc[h]));
                }
                __builtin_amdgcn_s_setprio(0);
            }
            if (t < end) {
                int s0 = srcs[t];
                v4h hs0v = *(const v4h*)&hA[((size_t)s0 * 64 + lane) * 4];
                _Float16 hs0e = hB[(size_t)s0 * 64 + lane];
                const h2* ap = easrt + (size_t)t * 8;
                h2 a0[8];
#pragma unroll
                for (int k2 = 0; k2 < 8; ++k2) a0[k2] = ap[k2];
                float hs0[NH];
#pragma unroll
                for (int h = 0; h < 4; ++h) hs0[h] = (float)hs0v[h];
                hs0[4] = (float)hs0e;
#pragma unroll
                for (int h = 0; h < NH; ++h) {
                    float v0 = hs0[h] + hd[h];
#pragma unroll
                    for (int k2 = 0; k2 < 8; ++k2)
                        v0 = __builtin_amdgcn_fdot2(a0[k2], we2[k2 * NH + h], v0, false);
                    float pe0 = exp2f(wave_sum_all(fmaf(fabsf(v0), attc4[h], v0 * attc6[h])));
                    l[h] += pe0;
                    acc[h] = fmaf(pe0, hs0[h], acc[h]);
                }
            }
            float o = 0.f;
#pragma unroll
            for (int h = 0; h < NH; ++h) o += acc[h] / l[h];
            o = o * 0.2f + bc;
            o = o > 0.f ? o : expm1f(o);
            if (outF) outF[(size_t)i * NC + lane] = o;
            else      outH[(size_t)i * NC + lane] = (_Float16)o;
        }
    }
}

// ---------------- launch ----------------
extern "C" void kernel_launch(void* const* d_in, const int* in_sizes, int n_in,
                              void* d_out, int out_size, void* d_ws, size_t ws_size,
                              hipStream_t stream) {
    const float* x     = (const float*)d_in[0];
    const int*   ei    = (const int*)d_in[1];
    const float* ea    = (const float*)d_in[2];
    const float* W0    = (const float*)d_in[3];
    const float* b0    = (const float*)d_in[4];
    const float* We0   = (const float*)d_in[5];
    const float* att0  = (const float*)d_in[6];
    const float* bias0 = (const float*)d_in[7];
    const float* W12   = (const float*)d_in[8];
    const float* b12   = (const float*)d_in[9];
    const float* We12  = (const float*)d_in[10];
    const float* att12 = (const float*)d_in[11];
    const float* bias12= (const float*)d_in[12];

    int N = in_sizes[0] / 128;
    int E = in_sizes[1] / 2;
    int R = E + N;
    int numWin = (R + CH - 1) / CH;
    int nb = (N + 1023) / 1024;
    const int* srcArr = ei;
    const int* dstArr = ei + E;

    char* ws = (char*)d_ws;
    size_t off = 0;
    auto alloc = [&](size_t bytes) -> void* {
        void* p = ws + off;
        off = (off + bytes + 255) & ~(size_t)255;
        return p;
    };
    int*      cnt     = (int*)alloc((size_t)N * 4);
    int*      offsets = (int*)alloc((size_t)(N + 1) * 4);
    int*      cursor  = (int*)alloc((size_t)N * 4);
    int*      selfSlot= (int*)alloc((size_t)N * 4);
    int*      blockSums=(int*)alloc((size_t)(nb + 1) * 4);
    _Float16* hbufA   = (_Float16*)alloc((size_t)N * 64 * 4 * 2); // [N][64][4] heads 0-3
    _Float16* hbufB   = (_Float16*)alloc((size_t)N * 64 * 2);     // [N][64]    head 4
    _Float16* acth    = (_Float16*)alloc((size_t)N * NC * 2);
    _Float16* Wth0    = (_Float16*)alloc((size_t)320 * 128 * 2);
    _Float16* Wth1    = (_Float16*)alloc((size_t)320 * 64 * 2);
    _Float16* Wth2    = (_Float16*)alloc((size_t)320 * 64 * 2);
    int*      winStart= (int*)alloc((size_t)(numWin + 1) * 4);
    h2*       easrt   = (h2*)alloc((size_t)R * 32);
    int*      srcs    = (int*)alloc((size_t)R * 4);

    (void)hipMemsetAsync(cnt, 0, (size_t)N * 4, stream);
    (void)hipMemsetAsync(winStart, 0x7f, (size_t)(numWin + 1) * 4, stream);
    count_kernel<<<(E + 255) / 256, 256, 0, stream>>>(dstArr, cnt, E);
    scan1_kernel<<<nb, 1024, 0, stream>>>(cnt, offsets, blockSums, N);
    scan2_kernel<<<1, 64, 0, stream>>>(blockSums, nb);
    scan3_kernel<<<(N + 255) / 256, 256, 0, stream>>>(offsets, cursor, blockSums, winStart, N, nb);
    scatter_kernel<<<(E + N + 255) / 256, 256, 0, stream>>>(srcArr, dstArr, ea, cursor,
                                                            srcs, easrt, selfSlot, N, E);
    loop_fill<<<((size_t)N * 8 + 255) / 256, 256, 0, stream>>>(offsets, selfSlot, easrt, N);
    transpose_w3<<<(320 * 256 + 255) / 256, 256, 0, stream>>>(W0, W12, Wth0, Wth1, Wth2);

    float* dout = (float*)d_out;
    int gemmBlocks = (N / 16 + 3) / 4 + 1;
    int fusedBlocks = (numWin + 3) / 4;   // one window per wave

    const _Float16* Ahs[3] = {nullptr, acth, acth};
    const float*    Afs[3] = {x, nullptr, nullptr};
    const _Float16* Bts[3] = {Wth0, Wth1, Wth2};
    int Ks[3] = {128, 64, 64};
    const float* bs[3]   = {b0, b12, b12 + HC};
    const float* Wes[3]  = {We0, We12, We12 + ED * HC};
    const float* atts[3] = {att0, att12, att12 + NH * NC};
    const float* bis[3]  = {bias0, bias12, bias12 + NC};
    for (int layer = 0; layer < 3; ++layer) {
        gemm_mfma<<<gemmBlocks, 256, 0, stream>>>(Ahs[layer], Afs[layer], Bts[layer], bs[layer],
                                                  hbufA, hbufB, N, Ks[layer]);
        gat_fused<<<fusedBlocks, 256, 0, stream>>>(hbufA, hbufB, offsets, srcs, easrt, winStart,
                                                   Wes[layer], atts[layer], bis[layer],
                                                   acth, (layer == 2) ? dout : nullptr, N, R);
    }
}